// Round 1
// baseline (427.616 us; speedup 1.0000x reference)
//
#include <hip/hip_runtime.h>
#include <cstdint>
#include <cstddef>

// SimpleGCN: h = x@W1+b1; 3x GCNConv(sym-norm adj w/ self loops); sigmoid(h@W2+b2)
// N=100000, d=128, E=1.6M.
// R13 = R12 + L2-side atomics for the histogram:
//   rocprof showed fusedA WRITE_SIZE=78MB (~49MB excess = 1.6M atomics x 32B
//   write granule) -> default device-scope atomicAdd executes MEMORY-side at
//   ~22G/s. Fix: per-XCD privatized histogram (8 copies, [xcd][node] layout,
//   line-disjoint) + __hip_atomic_fetch_add(.., __HIP_MEMORY_SCOPE_WORKGROUP)
//   so the RMW executes in the local XCD L2 (shared by all WGs on that XCD ->
//   atomic among the only writers of that copy). XCD id via s_getreg XCC_ID.
//   rank = (xcd<<12)|local_rank; scan3 emits per-node per-XCD offsets (xoff)
//   so scatter computes pos = row_ptr[c] + xoff[c][xcd] + local_rank.
//   deg = sum of 8 fixed-point partials (associative -> replay-stable).
// R12: fusedA = histo || gemmC0; scatter standalone at full occupancy.
// Algebra (R11): Wc0 = W1@Wg0 (front collapse), wc2 = Wg2@W2, c2 = bg2.W2+b2
//   (back collapse: layer-2 gather is a 4B scalar gather from L2-resident s[]).
// Replay stability (R6): no bf16 re-quantization of atomic-order-dependent
// sums -- h and s stay fp32; only deterministic GEMM outputs go bf16.

typedef __attribute__((ext_vector_type(8))) short bf16x8;
typedef __attribute__((ext_vector_type(4))) float f32x4;

// ---------- bf16 helpers (packed dword: low 16 bits = element 0) ----------
__device__ __forceinline__ unsigned f2bf(float f) {      // RNE float->bf16 bits
    unsigned u = __float_as_uint(f);
    u += 0x7fffu + ((u >> 16) & 1u);
    return u >> 16;
}
__device__ __forceinline__ float bf_lo(unsigned p) { return __uint_as_float(p << 16); }
__device__ __forceinline__ float bf_hi(unsigned p) { return __uint_as_float(p & 0xffff0000u); }

// ---------- prep (merged): Wt0 = (W1@Wg0)^T bf16, Wt1 = Wg1^T bf16,
//            wc2 = Wg2@W2, bc0 = b1@Wg0, c2 = bg2.W2+b2, zero packed (8 copies) ----------
__global__ void prep_kernel(const float* __restrict__ W1, const float* __restrict__ Wg,
                            const float* __restrict__ b1, const float* __restrict__ W2,
                            const float* __restrict__ bg, const float* __restrict__ b2,
                            unsigned short* __restrict__ Wt0, unsigned short* __restrict__ Wt1,
                            float* __restrict__ wc2, float* __restrict__ bc0,
                            float* __restrict__ c2,
                            unsigned long long* __restrict__ packed, int nz) {
    int idx = blockIdx.x * blockDim.x + threadIdx.x;
    if (idx < 16384) {              // Wt0[nn*128+k] = bf16((W1@Wg0)[k][nn])
        int nn = idx >> 7, k = idx & 127;
        float acc = 0.f;
        for (int j = 0; j < 128; ++j) acc += W1[k * 128 + j] * Wg[j * 128 + nn];
        Wt0[idx] = (unsigned short)f2bf(acc);
    } else if (idx < 32768) {       // Wt1[nn*128+k] = bf16(Wg1[k][nn])
        int t = idx - 16384;
        int nn = t >> 7, k = t & 127;
        Wt1[t] = (unsigned short)f2bf(Wg[16384 + k * 128 + nn]);
    } else if (idx < 32896) {       // wc2[k] = sum_j Wg2[k][j] * W2[j]
        int k = idx - 32768;
        float acc = 0.f;
        for (int j = 0; j < 128; ++j) acc += Wg[2 * 16384 + k * 128 + j] * W2[j];
        wc2[k] = acc;
    } else if (idx < 33024) {       // bc0[nn] = sum_j b1[j] * Wg0[j][nn]
        int nn = idx - 32896;
        float acc = 0.f;
        for (int j = 0; j < 128; ++j) acc += b1[j] * Wg[j * 128 + nn];
        bc0[nn] = acc;
    } else if (idx == 33024) {      // c2 = bg2 . W2 + b2
        float acc = b2[0];
        for (int j = 0; j < 128; ++j) acc += bg[256 + j] * W2[j];
        c2[0] = acc;
    }
    if (idx < nz) packed[idx] = 0ull;   // nz = 8*N (per-XCD copies)
}

// ---------- GEMM body (32x128 wave tile): C(bf16) = A(fp32) @ W (+bias) ----------
// No LDS/barriers; Wt (bf16 W^T) is L1/L2-resident; A converted in-register.
__device__ __forceinline__ void gemm_body32(const float* __restrict__ A,
                                            const unsigned short* __restrict__ Wt,
                                            const float* __restrict__ bias,
                                            unsigned short* __restrict__ C, int n, int blk) {
    int tid = threadIdx.x;
    int wave = tid >> 6, lane = tid & 63;
    int lm = lane & 15, g = lane >> 4;
    int m_base = blk * 128 + wave * 32;

    f32x4 acc[2][8];
#pragma unroll
    for (int rt = 0; rt < 2; ++rt)
#pragma unroll
        for (int ct = 0; ct < 8; ++ct) acc[rt][ct] = (f32x4){0.f, 0.f, 0.f, 0.f};

    size_t rowA[2];
    rowA[0] = (size_t)min(m_base + lm, n - 1);
    rowA[1] = (size_t)min(m_base + 16 + lm, n - 1);

#pragma unroll
    for (int kc = 0; kc < 4; ++kc) {
        int k0 = kc * 32 + g * 8;
        bf16x8 a[2];
#pragma unroll
        for (int rt = 0; rt < 2; ++rt) {
            const float* p = A + rowA[rt] * 128 + k0;
            float f[8];
            *(float4*)&f[0] = *(const float4*)p;
            *(float4*)&f[4] = *(const float4*)(p + 4);
            short sv[8];
#pragma unroll
            for (int j = 0; j < 8; ++j) sv[j] = (short)f2bf(f[j]);
            a[rt] = *(bf16x8*)sv;
        }
        bf16x8 b[8];
#pragma unroll
        for (int ct = 0; ct < 8; ++ct)
            b[ct] = *(const bf16x8*)(Wt + (ct * 16 + lm) * 128 + k0);
#pragma unroll
        for (int ct = 0; ct < 8; ++ct) {
            acc[0][ct] = __builtin_amdgcn_mfma_f32_16x16x32_bf16(a[0], b[ct], acc[0][ct], 0, 0, 0);
            acc[1][ct] = __builtin_amdgcn_mfma_f32_16x16x32_bf16(a[1], b[ct], acc[1][ct], 0, 0, 0);
        }
    }

#pragma unroll
    for (int rt = 0; rt < 2; ++rt) {
#pragma unroll
        for (int r = 0; r < 4; ++r) {
            int grow = m_base + rt * 16 + g * 4 + r;
            if (grow < n) {
#pragma unroll
                for (int ct = 0; ct < 8; ++ct) {
                    float v = acc[rt][ct][r];
                    if (bias) v += bias[ct * 16 + lm];
                    C[(size_t)grow * 128 + ct * 16 + lm] = (unsigned short)f2bf(v);
                }
            }
        }
    }
}

// ---------- fused A: histo (4 edges/thread, L2-side u64 atomic, rank) || gemmC0 ----------
// gemm blocks are b % K == 0 (b/K < nGemm); the rest are histo blocks.
// Histo: per-XCD privatized copies of packed[]; workgroup-scope atomic stays in
// the local XCD L2 (all writers of copy x are physically on XCD x -> atomic).
__global__ __launch_bounds__(256) void fusedA_kernel(const int* __restrict__ col,
                                                     const float* __restrict__ ewa,
                                                     unsigned long long* __restrict__ packed,
                                                     unsigned short* __restrict__ rank, int E,
                                                     const float* __restrict__ x,
                                                     const unsigned short* __restrict__ Wt0,
                                                     const float* __restrict__ bc0,
                                                     unsigned short* __restrict__ tbuf, int n,
                                                     int nGemm, int K) {
    int b = blockIdx.x;
    int g = b / K, r = b - g * K;
    if (r == 0 && g < nGemm) {
        gemm_body32(x, Wt0, bc0, tbuf, n, g);
    } else {
        unsigned xcd;
        asm volatile("s_getreg_b32 %0, hwreg(HW_REG_XCC_ID)" : "=s"(xcd));
        xcd &= 7u;
        unsigned long long* mypk = packed + (size_t)xcd * (size_t)n;

        int hb = b - min(g + (r > 0 ? 1 : 0), nGemm);
        int e0 = (hb * 256 + threadIdx.x) * 4;
        if (e0 + 3 < E) {
            int4   c4 = *(const int4*)(col + e0);
            float4 w4 = *(const float4*)(ewa + e0);
            int   c[4] = {c4.x, c4.y, c4.z, c4.w};
            float w[4] = {w4.x, w4.y, w4.z, w4.w};
            unsigned short rk[4];
#pragma unroll
            for (int i = 0; i < 4; ++i) {
                unsigned long long v = (1ull << 40) |
                    (unsigned long long)(unsigned)(w[i] * 16777216.0f);
                unsigned long long old = __hip_atomic_fetch_add(&mypk[c[i]], v,
                    __ATOMIC_RELAXED, __HIP_MEMORY_SCOPE_WORKGROUP);
                rk[i] = (unsigned short)((xcd << 12) | (unsigned)((old >> 40) & 0xfffu));
            }
            *(ushort4*)(rank + e0) = make_ushort4(rk[0], rk[1], rk[2], rk[3]);
        } else {
            for (int e = e0; e < E; ++e) {
                unsigned long long v = (1ull << 40) |
                    (unsigned long long)(unsigned)(ewa[e] * 16777216.0f);
                unsigned long long old = __hip_atomic_fetch_add(&mypk[col[e]], v,
                    __ATOMIC_RELAXED, __HIP_MEMORY_SCOPE_WORKGROUP);
                rank[e] = (unsigned short)((xcd << 12) | (unsigned)((old >> 40) & 0xfffu));
            }
        }
    }
}

// ---------- scatter standalone (NO atomics, full occupancy): 4 edges/thread ----------
// record = (src << 15) | (bf16(norm) & 0x7fff); norm > 0 so sign bit unused.
// pos = row_ptr[c] + xoff[c][xcd] + local_rank  (rank = (xcd<<12)|local).
__global__ __launch_bounds__(256) void scatter_kernel(const int* __restrict__ row,
                                                      const int* __restrict__ col,
                                                      const float* __restrict__ ew,
                                                      const float* __restrict__ dinv,
                                                      const int* __restrict__ row_ptr,
                                                      const unsigned short* __restrict__ rank,
                                                      const unsigned short* __restrict__ xoff,
                                                      unsigned* __restrict__ edata, int E) {
    int e0 = (blockIdx.x * 256 + threadIdx.x) * 4;
    if (e0 + 3 < E) {
        int4   r4 = *(const int4*)(row + e0);
        int4   c4 = *(const int4*)(col + e0);
        float4 w4 = *(const float4*)(ew + e0);
        ushort4 k4 = *(const ushort4*)(rank + e0);
        int   r[4] = {r4.x, r4.y, r4.z, r4.w};
        int   c[4] = {c4.x, c4.y, c4.z, c4.w};
        float w[4] = {w4.x, w4.y, w4.z, w4.w};
        unsigned short kk[4] = {k4.x, k4.y, k4.z, k4.w};
#pragma unroll
        for (int i = 0; i < 4; ++i) {
            float nrm = dinv[r[i]] * w[i] * dinv[c[i]];
            int pos = row_ptr[c[i]] + (int)xoff[(size_t)c[i] * 8 + (kk[i] >> 12)]
                      + (int)(kk[i] & 0xfffu);
            edata[pos] = ((unsigned)r[i] << 15) | (f2bf(nrm) & 0x7fffu);
        }
    } else {
        for (int e = e0; e < E; ++e) {
            int r = row[e], c = col[e];
            float nrm = dinv[r] * ew[e] * dinv[c];
            unsigned short k = rank[e];
            int pos = row_ptr[c] + (int)xoff[(size_t)c * 8 + (k >> 12)] + (int)(k & 0xfffu);
            edata[pos] = ((unsigned)r << 15) | (f2bf(nrm) & 0x7fffu);
        }
    }
}

// ---------- standalone GEMM (layer-1 messages): fp32 h @ Wt1 -> bf16 msgs ----------
__global__ __launch_bounds__(256) void gemm_mfma_kernel(const float* __restrict__ A,
                                                        const unsigned short* __restrict__ Wt,
                                                        unsigned short* __restrict__ C, int n) {
    gemm_body32(A, Wt, nullptr, C, n, blockIdx.x);
}

// ---------- scan phase 1: per-1024-chunk sums of PADDED counts (x8), 8 copies ----------
__global__ __launch_bounds__(256) void scan1_kernel(const unsigned long long* __restrict__ packed,
                                                    int* __restrict__ bsum, int n) {
    __shared__ int s[256];
    int b = blockIdx.x, t = threadIdx.x;
    int base = b * 1024 + t * 4;
    int acc = 0;
#pragma unroll
    for (int i = 0; i < 4; ++i)
        if (base + i < n) {
            int tot = 0;
#pragma unroll
            for (int x = 0; x < 8; ++x)
                tot += (int)(packed[(size_t)x * n + base + i] >> 40);
            acc += (tot + 7) & ~7;
        }
    s[t] = acc;
    __syncthreads();
    for (int off = 128; off > 0; off >>= 1) {
        if (t < off) s[t] += s[t + off];
        __syncthreads();
    }
    if (t == 0) bsum[b] = s[0];
}

// ---------- scan phase 3 (phase 2 folded): row_ptr + dinv + xoff + edata pad zero ----------
__global__ __launch_bounds__(256) void scan3_kernel(const unsigned long long* __restrict__ packed,
                                                    const int* __restrict__ bsum,
                                                    int* __restrict__ row_ptr,
                                                    float* __restrict__ dinv,
                                                    unsigned short* __restrict__ xoff,
                                                    unsigned* __restrict__ edata,
                                                    int n, int nblk) {
    __shared__ int s[256];
    int b = blockIdx.x, t = threadIdx.x;

    int bv = (t < nblk) ? bsum[t] : 0;
    s[t] = bv;
    __syncthreads();
    for (int off = 1; off < 256; off <<= 1) {
        int u = (t >= off) ? s[t - off] : 0;
        __syncthreads();
        s[t] += u;
        __syncthreads();
    }
    int boffb = (b == 0) ? 0 : s[b - 1];
    int total = s[nblk - 1];
    __syncthreads();

    int base = b * 1024 + t * 4;
    int c[4], v[4];
#pragma unroll
    for (int i = 0; i < 4; ++i) {
        c[i] = 0; v[i] = 0;
        if (base + i < n) {
            unsigned long long s40 = 0;
            int run0 = 0;
            unsigned short xo[8];
#pragma unroll
            for (int x = 0; x < 8; ++x) {
                unsigned long long pk = packed[(size_t)x * n + base + i];
                xo[x] = (unsigned short)run0;
                run0 += (int)(pk >> 40);
                s40 += pk & 0xFFFFFFFFFFull;
            }
            c[i] = run0;
            v[i] = (run0 + 7) & ~7;               // padded count
            *(ushort4*)(xoff + (size_t)(base + i) * 8)     = make_ushort4(xo[0], xo[1], xo[2], xo[3]);
            *(ushort4*)(xoff + (size_t)(base + i) * 8 + 4) = make_ushort4(xo[4], xo[5], xo[6], xo[7]);
            float deg = 1.0f + (float)s40 * (1.0f / 16777216.0f);
            dinv[base + i] = rsqrtf(deg);
        }
    }
    s[t] = v[0] + v[1] + v[2] + v[3];
    __syncthreads();
    for (int off = 1; off < 256; off <<= 1) {
        int u = (t >= off) ? s[t - off] : 0;
        __syncthreads();
        s[t] += u;
        __syncthreads();
    }
    int run = boffb + ((t == 0) ? 0 : s[t - 1]);
#pragma unroll
    for (int i = 0; i < 4; ++i) {
        if (base + i < n) {
            row_ptr[base + i] = run;
            for (int z = c[i]; z < v[i]; ++z) edata[run + z] = 0;   // zero pad slots
            run += v[i];
        }
    }
    if (b == nblk - 1 && t == 255) row_ptr[n] = total;
}

// ---------- aggregation: one wave per dest node, edge-pair batched gather ----------
// PROJECT=false: write fp32 h row. PROJECT=true: write s[wid] = h_row . wc2 (fp32).
template<bool PROJECT>
__global__ __launch_bounds__(256) void aggregate_kernel(const uint2* __restrict__ tb2,
                                                        const int* __restrict__ row_ptr,
                                                        const unsigned* __restrict__ edata,
                                                        const float* __restrict__ dinv,
                                                        const float* __restrict__ bias,
                                                        const float* __restrict__ wc2,
                                                        void* __restrict__ out, int n) {
    int wid  = (int)((blockIdx.x * (size_t)blockDim.x + threadIdx.x) >> 6);
    int lane = threadIdx.x & 63;
    if (wid >= n) return;
    int half = lane >> 5;     // which edge of each pair
    int fl   = lane & 31;     // feature group (4 feats)

    float a0 = 0.f, a1 = 0.f, a2 = 0.f, a3 = 0.f;

    int start = row_ptr[wid], end = row_ptr[wid + 1];
    for (int base = start; base < end; base += 64) {
        unsigned ed = edata[base + lane];     // over-read into next buckets is harmless
        int m = end - base; if (m > 64) m = 64;
        int j = 0;
        for (; j + 16 <= m; j += 16) {        // 8 pairs = 16 edges
            unsigned p[8]; uint2 u[8];
#pragma unroll
            for (int k = 0; k < 8; ++k) p[k] = __shfl(ed, j + 2 * k + half);
#pragma unroll
            for (int k = 0; k < 8; ++k) u[k] = tb2[(size_t)(p[k] >> 15) * 32 + fl];
#pragma unroll
            for (int k = 0; k < 8; ++k) {
                float w = __uint_as_float((p[k] & 0x7fffu) << 16);
                a0 += w * bf_lo(u[k].x); a1 += w * bf_hi(u[k].x);
                a2 += w * bf_lo(u[k].y); a3 += w * bf_hi(u[k].y);
            }
        }
        for (; j < m; j += 8) {               // 4 pairs = 8 edges (m is mult of 8)
            unsigned p[4]; uint2 u[4];
#pragma unroll
            for (int k = 0; k < 4; ++k) p[k] = __shfl(ed, j + 2 * k + half);
#pragma unroll
            for (int k = 0; k < 4; ++k) u[k] = tb2[(size_t)(p[k] >> 15) * 32 + fl];
#pragma unroll
            for (int k = 0; k < 4; ++k) {
                float w = __uint_as_float((p[k] & 0x7fffu) << 16);
                a0 += w * bf_lo(u[k].x); a1 += w * bf_hi(u[k].x);
                a2 += w * bf_lo(u[k].y); a3 += w * bf_hi(u[k].y);
            }
        }
    }
    // combine the two halves (lanes l and l^32 end up with identical sums)
    a0 += __shfl_xor(a0, 32); a1 += __shfl_xor(a1, 32);
    a2 += __shfl_xor(a2, 32); a3 += __shfl_xor(a3, 32);

    // self-loop + bias (mirrored across halves)
    float di = dinv[wid];
    float sn = di * di;
    uint2 ts = tb2[(size_t)wid * 32 + fl];
    a0 += sn * bf_lo(ts.x); a1 += sn * bf_hi(ts.x);
    a2 += sn * bf_lo(ts.y); a3 += sn * bf_hi(ts.y);
    float4 bb = ((const float4*)bias)[fl];
    a0 += bb.x; a1 += bb.y; a2 += bb.z; a3 += bb.w;

    if (PROJECT) {
        float4 wv = ((const float4*)wc2)[fl];
        float d = a0 * wv.x + a1 * wv.y + a2 * wv.z + a3 * wv.w;
        if (half) d = 0.f;                    // halves mirror: count once
#pragma unroll
        for (int off = 32; off > 0; off >>= 1) d += __shfl_xor(d, off);
        if (lane == 0) ((float*)out)[wid] = d;     // s[wid], fp32
    } else if (half == 0) {
        float4 o; o.x = a0; o.y = a1; o.z = a2; o.w = a3;
        ((float4*)out)[(size_t)wid * 32 + fl] = o; // fp32 h state
    }
}

// ---------- final: scalar gather  out[i] = sigmoid( A s + c2 ) ----------
__global__ __launch_bounds__(256) void aggFinal_kernel(const float* __restrict__ s,
                                                       const int* __restrict__ row_ptr,
                                                       const unsigned* __restrict__ edata,
                                                       const float* __restrict__ dinv,
                                                       const float* __restrict__ c2,
                                                       float* __restrict__ out, int n) {
    int wid  = (int)((blockIdx.x * (size_t)blockDim.x + threadIdx.x) >> 6);
    int lane = threadIdx.x & 63;
    if (wid >= n) return;
    int start = row_ptr[wid], end = row_ptr[wid + 1];
    float acc = 0.f;
    for (int base = start; base < end; base += 64) {
        int idx = base + lane;
        if (idx < end) {                      // pads have norm=0 -> harmless
            unsigned ed = edata[idx];
            float w = __uint_as_float((ed & 0x7fffu) << 16);
            acc += w * s[ed >> 15];
        }
    }
#pragma unroll
    for (int off = 32; off > 0; off >>= 1) acc += __shfl_xor(acc, off);
    if (lane == 0) {
        float di = dinv[wid];
        float d = acc + di * di * s[wid] + c2[0];
        out[wid] = 1.0f / (1.0f + expf(-d));
    }
}

static inline char* align16(char* p) { return (char*)(((uintptr_t)p + 15) & ~(uintptr_t)15); }

extern "C" void kernel_launch(void* const* d_in, const int* in_sizes, int n_in,
                              void* d_out, int out_size, void* d_ws, size_t ws_size,
                              hipStream_t stream) {
    const float* x  = (const float*)d_in[0];
    const int*   ei = (const int*)d_in[1];   // [2, E] int32
    const float* ea = (const float*)d_in[2]; // [E]
    const float* W1 = (const float*)d_in[3];
    const float* b1 = (const float*)d_in[4];
    const float* Wg = (const float*)d_in[5]; // [3,128,128]
    const float* bg = (const float*)d_in[6]; // [3,128]
    const float* W2 = (const float*)d_in[7]; // [128]
    const float* b2 = (const float*)d_in[8]; // [1]

    const int N = in_sizes[0] / 128;
    const int E = in_sizes[2];
    const int Npad = (N + 127) & ~127;
    const int* row = ei;
    const int* col = ei + E;

    // workspace layout
    char* p = (char*)d_ws;
    float*          hbuf = (float*)p;          p += (size_t)Npad * 128 * 4;  // fp32 h state
    unsigned short* tbuf = (unsigned short*)p; p += (size_t)Npad * 128 * 2;  // bf16 messages
    unsigned short* wbuf = (unsigned short*)p; p += 2 * 16384 * 2;           // Wt0(=Wc0^T), Wt1
    float* bc0 = (float*)p;  p += 128 * 4;
    float* wc2 = (float*)p;  p += 128 * 4;
    float* c2  = (float*)p;  p += 16;
    float* sbuf = (float*)p; p += (size_t)N * 4;
    p = align16(p);
    unsigned long long* packed = (unsigned long long*)p; p += (size_t)N * 8 * 8;  // 8 XCD copies
    float* dinv   = (float*)p; p += (size_t)N * 4;
    int* row_ptr  = (int*)p;   p += (size_t)(N + 1) * 4; p = align16(p);
    int* bsum     = (int*)p;   p += 256 * 4;
    unsigned short* xoff = (unsigned short*)p; p += (size_t)N * 8 * 2;       // per-node per-XCD offsets
    unsigned short* rank = (unsigned short*)p; p += (size_t)E * 2; p = align16(p);
    unsigned* edata = (unsigned*)p;                    // E + 7N + 64 padded records

    dim3 b256(256);
    int nblk  = (N + 1023) / 1024;          // 98 (<=256)
    int nGemm = Npad / 128;                 // 782
    int nHist = (E + 1023) / 1024;          // 1563 (4 edges/thread)
    int nScat = (E + 1023) / 1024;          // 1563
    int nZero = 8 * N;
    int nPrep = (max(nZero, 33025) + 255) / 256;

    int gridA = nHist + nGemm;
    int KA    = (gridA + nGemm - 1) / nGemm;   // 3

    prep_kernel<<<nPrep, b256, 0, stream>>>(W1, Wg, b1, W2, bg, b2,
                                            wbuf, wbuf + 16384, wc2, bc0, c2, packed, nZero);
    fusedA_kernel<<<gridA, b256, 0, stream>>>(col, ea, packed, rank, E,
                                              x, wbuf, bc0, tbuf, N, nGemm, KA);
    scan1_kernel<<<nblk, b256, 0, stream>>>(packed, bsum, N);
    scan3_kernel<<<nblk, b256, 0, stream>>>(packed, bsum, row_ptr, dinv, xoff, edata, N, nblk);
    scatter_kernel<<<nScat, b256, 0, stream>>>(row, col, ea, dinv, row_ptr, rank, xoff, edata, E);

    int wave_blocks = (int)(((size_t)N * 64 + 255) / 256);

    // agg0 -> hbuf(fp32); gemm(Wg1) -> tbuf; agg1+project -> sbuf; final scalar gather
    aggregate_kernel<false><<<wave_blocks, b256, 0, stream>>>(
        (const uint2*)tbuf, row_ptr, edata, dinv, bg, nullptr, hbuf, N);
    gemm_mfma_kernel<<<nGemm, b256, 0, stream>>>(hbuf, wbuf + 16384, tbuf, N);
    aggregate_kernel<true><<<wave_blocks, b256, 0, stream>>>(
        (const uint2*)tbuf, row_ptr, edata, dinv, bg + 128, wc2, sbuf, N);
    aggFinal_kernel<<<wave_blocks, b256, 0, stream>>>(sbuf, row_ptr, edata, dinv, c2,
                                                      (float*)d_out, N);
}

// Round 2
// 427.138 us; speedup vs baseline: 1.0011x; 1.0011x over previous
//
#include <hip/hip_runtime.h>
#include <cstdint>
#include <cstddef>

// SimpleGCN: h = x@W1+b1; 3x GCNConv(sym-norm adj w/ self loops); sigmoid(h@W2+b2)
// N=100000, d=128, E=1.6M.
// R14: REMOVE the global-atomic histogram entirely (R13 post-mortem: returning
//   u64 atomics execute memory-side regardless of scope; WRITE_SIZE excess
//   49MB = 1.6M x 32B granule; rate pinned ~22G/s -> 74us floor). Replace
//   histo+scan1+scan3+scatter (~132us) with an LDS two-level counting sort:
//     bucketCount:  per-8192-edge block LDS histogram over NB=ceil(N/128)
//                   buckets -> cnt1[chunk][bucket]
//     colScan:      per-bucket exclusive prefix over chunks (in-place) + totals
//     bucketScatter: cursors = bucketStart+chunkOffset (in-block scan), LDS
//                   fetch_add slots, write rec=(src,col_low,ew_f32) u64
//     nodeCount:    per-bucket LDS node counts + fixed-point deg -> cnt, dinv,
//                   padTotal (deterministic u32 adds)
//     finalize:     in-block scans -> row_ptr + pad zeroing + scatter
//                   (src, bf16(norm)) into edata via LDS cursors
//   Zero global atomics anywhere. gemmC0 standalone (R12 showed fusion with
//   histo bought ~nothing: 93 vs 74+20).
// Algebra (R11): Wc0 = W1@Wg0 (front collapse), wc2 = Wg2@W2, c2 = bg2.W2+b2
//   (back collapse: layer-2 gather is a 4B scalar gather from L2-resident s[]).
// Replay stability (R6): no bf16 re-quantization of atomic-order-dependent
// sums -- h and s stay fp32; only deterministic GEMM outputs go bf16.
// rec[] aliases hbuf[] (rec dead before agg0 writes hbuf).

typedef __attribute__((ext_vector_type(8))) short bf16x8;
typedef __attribute__((ext_vector_type(4))) float f32x4;

// ---------- bf16 helpers (packed dword: low 16 bits = element 0) ----------
__device__ __forceinline__ unsigned f2bf(float f) {      // RNE float->bf16 bits
    unsigned u = __float_as_uint(f);
    u += 0x7fffu + ((u >> 16) & 1u);
    return u >> 16;
}
__device__ __forceinline__ float bf_lo(unsigned p) { return __uint_as_float(p << 16); }
__device__ __forceinline__ float bf_hi(unsigned p) { return __uint_as_float(p & 0xffff0000u); }

// ---------- prep (merged): Wt0 = (W1@Wg0)^T bf16, Wt1 = Wg1^T bf16,
//            wc2 = Wg2@W2, bc0 = b1@Wg0, c2 = bg2.W2+b2 ----------
__global__ void prep_kernel(const float* __restrict__ W1, const float* __restrict__ Wg,
                            const float* __restrict__ b1, const float* __restrict__ W2,
                            const float* __restrict__ bg, const float* __restrict__ b2,
                            unsigned short* __restrict__ Wt0, unsigned short* __restrict__ Wt1,
                            float* __restrict__ wc2, float* __restrict__ bc0,
                            float* __restrict__ c2) {
    int idx = blockIdx.x * blockDim.x + threadIdx.x;
    if (idx < 16384) {              // Wt0[nn*128+k] = bf16((W1@Wg0)[k][nn])
        int nn = idx >> 7, k = idx & 127;
        float acc = 0.f;
        for (int j = 0; j < 128; ++j) acc += W1[k * 128 + j] * Wg[j * 128 + nn];
        Wt0[idx] = (unsigned short)f2bf(acc);
    } else if (idx < 32768) {       // Wt1[nn*128+k] = bf16(Wg1[k][nn])
        int t = idx - 16384;
        int nn = t >> 7, k = t & 127;
        Wt1[t] = (unsigned short)f2bf(Wg[16384 + k * 128 + nn]);
    } else if (idx < 32896) {       // wc2[k] = sum_j Wg2[k][j] * W2[j]
        int k = idx - 32768;
        float acc = 0.f;
        for (int j = 0; j < 128; ++j) acc += Wg[2 * 16384 + k * 128 + j] * W2[j];
        wc2[k] = acc;
    } else if (idx < 33024) {       // bc0[nn] = sum_j b1[j] * Wg0[j][nn]
        int nn = idx - 32896;
        float acc = 0.f;
        for (int j = 0; j < 128; ++j) acc += b1[j] * Wg[j * 128 + nn];
        bc0[nn] = acc;
    } else if (idx == 33024) {      // c2 = bg2 . W2 + b2
        float acc = b2[0];
        for (int j = 0; j < 128; ++j) acc += bg[256 + j] * W2[j];
        c2[0] = acc;
    }
}

// ---------- GEMM body (32x128 wave tile): C(bf16) = A(fp32) @ W (+bias) ----------
// No LDS/barriers; Wt (bf16 W^T) is L1/L2-resident; A converted in-register.
__device__ __forceinline__ void gemm_body32(const float* __restrict__ A,
                                            const unsigned short* __restrict__ Wt,
                                            const float* __restrict__ bias,
                                            unsigned short* __restrict__ C, int n, int blk) {
    int tid = threadIdx.x;
    int wave = tid >> 6, lane = tid & 63;
    int lm = lane & 15, g = lane >> 4;
    int m_base = blk * 128 + wave * 32;

    f32x4 acc[2][8];
#pragma unroll
    for (int rt = 0; rt < 2; ++rt)
#pragma unroll
        for (int ct = 0; ct < 8; ++ct) acc[rt][ct] = (f32x4){0.f, 0.f, 0.f, 0.f};

    size_t rowA[2];
    rowA[0] = (size_t)min(m_base + lm, n - 1);
    rowA[1] = (size_t)min(m_base + 16 + lm, n - 1);

#pragma unroll
    for (int kc = 0; kc < 4; ++kc) {
        int k0 = kc * 32 + g * 8;
        bf16x8 a[2];
#pragma unroll
        for (int rt = 0; rt < 2; ++rt) {
            const float* p = A + rowA[rt] * 128 + k0;
            float f[8];
            *(float4*)&f[0] = *(const float4*)p;
            *(float4*)&f[4] = *(const float4*)(p + 4);
            short sv[8];
#pragma unroll
            for (int j = 0; j < 8; ++j) sv[j] = (short)f2bf(f[j]);
            a[rt] = *(bf16x8*)sv;
        }
        bf16x8 b[8];
#pragma unroll
        for (int ct = 0; ct < 8; ++ct)
            b[ct] = *(const bf16x8*)(Wt + (ct * 16 + lm) * 128 + k0);
#pragma unroll
        for (int ct = 0; ct < 8; ++ct) {
            acc[0][ct] = __builtin_amdgcn_mfma_f32_16x16x32_bf16(a[0], b[ct], acc[0][ct], 0, 0, 0);
            acc[1][ct] = __builtin_amdgcn_mfma_f32_16x16x32_bf16(a[1], b[ct], acc[1][ct], 0, 0, 0);
        }
    }

#pragma unroll
    for (int rt = 0; rt < 2; ++rt) {
#pragma unroll
        for (int r = 0; r < 4; ++r) {
            int grow = m_base + rt * 16 + g * 4 + r;
            if (grow < n) {
#pragma unroll
                for (int ct = 0; ct < 8; ++ct) {
                    float v = acc[rt][ct][r];
                    if (bias) v += bias[ct * 16 + lm];
                    C[(size_t)grow * 128 + ct * 16 + lm] = (unsigned short)f2bf(v);
                }
            }
        }
    }
}

__global__ __launch_bounds__(256) void gemm_mfma_kernel(const float* __restrict__ A,
                                                        const unsigned short* __restrict__ Wt,
                                                        const float* __restrict__ bias,
                                                        unsigned short* __restrict__ C, int n) {
    gemm_body32(A, Wt, bias, C, n, blockIdx.x);
}

// ---------- CSR build, step 1: per-chunk bucket histogram (LDS only) ----------
// chunk = 8192 edges (32/thread); bucket = 128 consecutive nodes (col>>7).
__global__ __launch_bounds__(256) void bucketCount_kernel(const int* __restrict__ col,
                                                          unsigned* __restrict__ cnt1,
                                                          int E, int NB) {
    __shared__ unsigned cnt[1024];
    int b = blockIdx.x, t = threadIdx.x;
    for (int i = t; i < NB; i += 256) cnt[i] = 0;
    __syncthreads();
    int base = b * 8192;
#pragma unroll 4
    for (int i = 0; i < 32; ++i) {
        int e = base + i * 256 + t;
        if (e < E) atomicAdd(&cnt[(unsigned)col[e] >> 7], 1u);
    }
    __syncthreads();
    for (int i = t; i < NB; i += 256) cnt1[(size_t)b * NB + i] = cnt[i];
}

// ---------- step 2: per-bucket exclusive prefix over chunks (in place) ----------
__global__ __launch_bounds__(256) void colScan_kernel(unsigned* __restrict__ cb,
                                                      unsigned* __restrict__ total,
                                                      int NB, int NC) {
    int b = blockIdx.x * 256 + threadIdx.x;
    if (b >= NB) return;
    unsigned run = 0;
    int j = 0;
    for (; j + 4 <= NC; j += 4) {                    // 4-way unroll: batch the loads
        size_t i0 = (size_t)j * NB + b;
        unsigned c0 = cb[i0], c1 = cb[i0 + NB], c2v = cb[i0 + 2 * (size_t)NB],
                 c3 = cb[i0 + 3 * (size_t)NB];
        cb[i0] = run;                   run += c0;
        cb[i0 + NB] = run;              run += c1;
        cb[i0 + 2 * (size_t)NB] = run;  run += c2v;
        cb[i0 + 3 * (size_t)NB] = run;  run += c3;
    }
    for (; j < NC; ++j) {
        size_t i0 = (size_t)j * NB + b;
        unsigned c = cb[i0]; cb[i0] = run; run += c;
    }
    total[b] = run;
}

// ---------- in-block helper: pre = sum(arr[0..b-1]), gt = sum(arr[0..NB-1]) ----------
__device__ __forceinline__ unsigned blk_prefix(const unsigned* __restrict__ arr, int NB, int b,
                                               unsigned* sc, unsigned* gt) {
    int t = threadIdx.x;
    unsigned s = 0;
    int i0 = t * 4;
#pragma unroll
    for (int k = 0; k < 4; ++k) { int i = i0 + k; if (i < NB) s += arr[i]; }
    sc[t] = s;
    __syncthreads();
    for (int off = 1; off < 256; off <<= 1) {
        unsigned u = (t >= off) ? sc[t - off] : 0;
        __syncthreads();
        sc[t] += u;
        __syncthreads();
    }
    unsigned pre = 0;
    int bq = b >> 2;
    if (bq) pre = sc[bq - 1];
    for (int i = bq * 4; i < b; ++i) pre += arr[i];   // <=3 L2-hot reads
    if (gt) *gt = sc[255];
    unsigned r = pre;
    __syncthreads();                                  // sc reusable after return
    return r;
}

// ---------- step 3: scatter edges into bucket-ordered rec[] (LDS cursors) ----------
// rec = ((src<<7 | col&127) << 32) | f32bits(ew)
__global__ __launch_bounds__(256) void bucketScatter_kernel(const int* __restrict__ row,
        const int* __restrict__ col, const float* __restrict__ ew,
        const unsigned* __restrict__ offs0, const unsigned* __restrict__ total,
        unsigned long long* __restrict__ rec, int E, int NB) {
    __shared__ unsigned cur[1024];
    __shared__ unsigned sc[256];
    int b = blockIdx.x, t = threadIdx.x;
    int i0 = t * 4;
    unsigned v0 = (i0 < NB) ? total[i0] : 0;
    unsigned v1 = (i0 + 1 < NB) ? total[i0 + 1] : 0;
    unsigned v2 = (i0 + 2 < NB) ? total[i0 + 2] : 0;
    unsigned v3 = (i0 + 3 < NB) ? total[i0 + 3] : 0;
    sc[t] = v0 + v1 + v2 + v3;
    __syncthreads();
    for (int off = 1; off < 256; off <<= 1) {
        unsigned u = (t >= off) ? sc[t - off] : 0;
        __syncthreads();
        sc[t] += u;
        __syncthreads();
    }
    unsigned bs = (t == 0) ? 0 : sc[t - 1];
    if (i0 < NB)     cur[i0]     = bs                 + offs0[(size_t)b * NB + i0];
    if (i0 + 1 < NB) cur[i0 + 1] = bs + v0            + offs0[(size_t)b * NB + i0 + 1];
    if (i0 + 2 < NB) cur[i0 + 2] = bs + v0 + v1       + offs0[(size_t)b * NB + i0 + 2];
    if (i0 + 3 < NB) cur[i0 + 3] = bs + v0 + v1 + v2  + offs0[(size_t)b * NB + i0 + 3];
    __syncthreads();
    int base = b * 8192;
#pragma unroll 4
    for (int i = 0; i < 32; ++i) {
        int e = base + i * 256 + t;
        if (e < E) {
            unsigned c = (unsigned)col[e];
            unsigned pos = atomicAdd(&cur[c >> 7], 1u);
            unsigned long long r = ((unsigned long long)(((unsigned)row[e] << 7) | (c & 127u)) << 32)
                                 | (unsigned long long)__float_as_uint(ew[e]);
            rec[pos] = r;
        }
    }
}

// ---------- step 4: per-bucket node counts + deg (fixed point, deterministic) ----------
__global__ __launch_bounds__(256) void nodeCount_kernel(const unsigned long long* __restrict__ rec,
        const unsigned* __restrict__ total, unsigned* __restrict__ cntg,
        float* __restrict__ dinv, unsigned* __restrict__ padTotal, int n, int NB) {
    __shared__ unsigned sc[256];
    __shared__ unsigned lcnt[128];
    __shared__ unsigned ldeg[128];
    int b = blockIdx.x, t = threadIdx.x;
    unsigned rstart = blk_prefix(total, NB, b, sc, nullptr);
    unsigned nb = total[b];
    if (t < 128) { lcnt[t] = 0; ldeg[t] = 0; }
    __syncthreads();
    for (unsigned i = t; i < nb; i += 256) {
        unsigned long long r = rec[rstart + i];
        unsigned key = (unsigned)(r >> 32);
        unsigned cl = key & 127u;
        float w = __uint_as_float((unsigned)r);
        atomicAdd(&lcnt[cl], 1u);
        atomicAdd(&ldeg[cl], (unsigned)(w * 16777216.0f));   // same truncation as R12
    }
    __syncthreads();
    int node = b * 128 + t;
    unsigned pv = 0;
    if (t < 128 && node < n) {
        unsigned c = lcnt[t];
        cntg[node] = c;
        dinv[node] = rsqrtf(1.0f + (float)ldeg[t] * (1.0f / 16777216.0f));
        pv = (c + 7) & ~7u;
    }
    sc[t] = pv;
    __syncthreads();
    for (int off = 128; off > 0; off >>= 1) {
        if (t < off) sc[t] += sc[t + off];
        __syncthreads();
    }
    if (t == 0) padTotal[b] = sc[0];
}

// ---------- step 5: row_ptr + pad zero + final edata scatter (norm bf16) ----------
// record = (src << 15) | (bf16(norm) & 0x7fff); norm >= 0 so sign bit unused.
__global__ __launch_bounds__(256) void finalize_kernel(const unsigned long long* __restrict__ rec,
        const unsigned* __restrict__ total, const unsigned* __restrict__ padTotal,
        const unsigned* __restrict__ cntg, const float* __restrict__ dinv,
        int* __restrict__ row_ptr, unsigned* __restrict__ edata, int n, int NB) {
    __shared__ unsigned sc[256];
    __shared__ unsigned curp[128];
    __shared__ float sdv[128];
    __shared__ unsigned lpre[128];
    int b = blockIdx.x, t = threadIdx.x;
    unsigned gt;
    unsigned rstart = blk_prefix(total, NB, b, sc, nullptr);
    unsigned nb = total[b];
    unsigned ebase = blk_prefix(padTotal, NB, b, sc, &gt);

    int node = b * 128 + t;
    unsigned c = 0, pv = 0;
    if (t < 128) {
        c = (node < n) ? cntg[node] : 0;
        pv = (c + 7) & ~7u;
        lpre[t] = pv;
    }
    __syncthreads();
    for (int off = 1; off < 128; off <<= 1) {          // inclusive scan over 128
        unsigned u = (t < 128 && t >= off) ? lpre[t - off] : 0;
        __syncthreads();
        if (t < 128) lpre[t] += u;
        __syncthreads();
    }
    if (t < 128 && node < n) {
        unsigned st = ebase + lpre[t] - pv;            // exclusive
        row_ptr[node] = (int)st;
        curp[t] = st;
        sdv[t] = dinv[node];
        for (unsigned z = c; z < pv; ++z) edata[st + z] = 0;   // zero pad slots
    }
    if (b == NB - 1 && t == 0) row_ptr[n] = (int)gt;
    __syncthreads();
    for (unsigned i = t; i < nb; i += 256) {
        unsigned long long r = rec[rstart + i];
        unsigned key = (unsigned)(r >> 32);
        unsigned cl = key & 127u, src = key >> 7;
        float w = __uint_as_float((unsigned)r);
        float nrm = dinv[src] * w * sdv[cl];           // same multiply order as R12
        unsigned pos = atomicAdd(&curp[cl], 1u);       // LDS cursor
        edata[pos] = (src << 15) | (f2bf(nrm) & 0x7fffu);
    }
}

// ---------- aggregation: one wave per dest node, edge-pair batched gather ----------
// PROJECT=false: write fp32 h row. PROJECT=true: write s[wid] = h_row . wc2 (fp32).
template<bool PROJECT>
__global__ __launch_bounds__(256) void aggregate_kernel(const uint2* __restrict__ tb2,
                                                        const int* __restrict__ row_ptr,
                                                        const unsigned* __restrict__ edata,
                                                        const float* __restrict__ dinv,
                                                        const float* __restrict__ bias,
                                                        const float* __restrict__ wc2,
                                                        void* __restrict__ out, int n) {
    int wid  = (int)((blockIdx.x * (size_t)blockDim.x + threadIdx.x) >> 6);
    int lane = threadIdx.x & 63;
    if (wid >= n) return;
    int half = lane >> 5;     // which edge of each pair
    int fl   = lane & 31;     // feature group (4 feats)

    float a0 = 0.f, a1 = 0.f, a2 = 0.f, a3 = 0.f;

    int start = row_ptr[wid], end = row_ptr[wid + 1];
    for (int base = start; base < end; base += 64) {
        unsigned ed = edata[base + lane];     // over-read into next buckets is harmless
        int m = end - base; if (m > 64) m = 64;
        int j = 0;
        for (; j + 16 <= m; j += 16) {        // 8 pairs = 16 edges
            unsigned p[8]; uint2 u[8];
#pragma unroll
            for (int k = 0; k < 8; ++k) p[k] = __shfl(ed, j + 2 * k + half);
#pragma unroll
            for (int k = 0; k < 8; ++k) u[k] = tb2[(size_t)(p[k] >> 15) * 32 + fl];
#pragma unroll
            for (int k = 0; k < 8; ++k) {
                float w = __uint_as_float((p[k] & 0x7fffu) << 16);
                a0 += w * bf_lo(u[k].x); a1 += w * bf_hi(u[k].x);
                a2 += w * bf_lo(u[k].y); a3 += w * bf_hi(u[k].y);
            }
        }
        for (; j < m; j += 8) {               // 4 pairs = 8 edges (m is mult of 8)
            unsigned p[4]; uint2 u[4];
#pragma unroll
            for (int k = 0; k < 4; ++k) p[k] = __shfl(ed, j + 2 * k + half);
#pragma unroll
            for (int k = 0; k < 4; ++k) u[k] = tb2[(size_t)(p[k] >> 15) * 32 + fl];
#pragma unroll
            for (int k = 0; k < 4; ++k) {
                float w = __uint_as_float((p[k] & 0x7fffu) << 16);
                a0 += w * bf_lo(u[k].x); a1 += w * bf_hi(u[k].x);
                a2 += w * bf_lo(u[k].y); a3 += w * bf_hi(u[k].y);
            }
        }
    }
    // combine the two halves (lanes l and l^32 end up with identical sums)
    a0 += __shfl_xor(a0, 32); a1 += __shfl_xor(a1, 32);
    a2 += __shfl_xor(a2, 32); a3 += __shfl_xor(a3, 32);

    // self-loop + bias (mirrored across halves)
    float di = dinv[wid];
    float sn = di * di;
    uint2 ts = tb2[(size_t)wid * 32 + fl];
    a0 += sn * bf_lo(ts.x); a1 += sn * bf_hi(ts.x);
    a2 += sn * bf_lo(ts.y); a3 += sn * bf_hi(ts.y);
    float4 bb = ((const float4*)bias)[fl];
    a0 += bb.x; a1 += bb.y; a2 += bb.z; a3 += bb.w;

    if (PROJECT) {
        float4 wv = ((const float4*)wc2)[fl];
        float d = a0 * wv.x + a1 * wv.y + a2 * wv.z + a3 * wv.w;
        if (half) d = 0.f;                    // halves mirror: count once
#pragma unroll
        for (int off = 32; off > 0; off >>= 1) d += __shfl_xor(d, off);
        if (lane == 0) ((float*)out)[wid] = d;     // s[wid], fp32
    } else if (half == 0) {
        float4 o; o.x = a0; o.y = a1; o.z = a2; o.w = a3;
        ((float4*)out)[(size_t)wid * 32 + fl] = o; // fp32 h state
    }
}

// ---------- final: scalar gather  out[i] = sigmoid( A s + c2 ) ----------
__global__ __launch_bounds__(256) void aggFinal_kernel(const float* __restrict__ s,
                                                       const int* __restrict__ row_ptr,
                                                       const unsigned* __restrict__ edata,
                                                       const float* __restrict__ dinv,
                                                       const float* __restrict__ c2,
                                                       float* __restrict__ out, int n) {
    int wid  = (int)((blockIdx.x * (size_t)blockDim.x + threadIdx.x) >> 6);
    int lane = threadIdx.x & 63;
    if (wid >= n) return;
    int start = row_ptr[wid], end = row_ptr[wid + 1];
    float acc = 0.f;
    for (int base = start; base < end; base += 64) {
        int idx = base + lane;
        if (idx < end) {                      // pads have norm=0 -> harmless
            unsigned ed = edata[idx];
            float w = __uint_as_float((ed & 0x7fffu) << 16);
            acc += w * s[ed >> 15];
        }
    }
#pragma unroll
    for (int off = 32; off > 0; off >>= 1) acc += __shfl_xor(acc, off);
    if (lane == 0) {
        float di = dinv[wid];
        float d = acc + di * di * s[wid] + c2[0];
        out[wid] = 1.0f / (1.0f + expf(-d));
    }
}

static inline char* align16(char* p) { return (char*)(((uintptr_t)p + 15) & ~(uintptr_t)15); }

extern "C" void kernel_launch(void* const* d_in, const int* in_sizes, int n_in,
                              void* d_out, int out_size, void* d_ws, size_t ws_size,
                              hipStream_t stream) {
    const float* x  = (const float*)d_in[0];
    const int*   ei = (const int*)d_in[1];   // [2, E] int32
    const float* ea = (const float*)d_in[2]; // [E]
    const float* W1 = (const float*)d_in[3];
    const float* b1 = (const float*)d_in[4];
    const float* Wg = (const float*)d_in[5]; // [3,128,128]
    const float* bg = (const float*)d_in[6]; // [3,128]
    const float* W2 = (const float*)d_in[7]; // [128]
    const float* b2 = (const float*)d_in[8]; // [1]

    const int N = in_sizes[0] / 128;
    const int E = in_sizes[2];
    const int Npad = (N + 127) & ~127;
    const int* row = ei;
    const int* col = ei + E;

    const int NB = (N + 127) >> 7;           // buckets of 128 nodes (782; <=1024)
    const int NC = (E + 8191) >> 13;         // 8192-edge chunks (196)

    // workspace layout
    char* p = (char*)d_ws;
    float*          hbuf = (float*)p;          p += (size_t)Npad * 128 * 4;  // fp32 h state
    unsigned long long* rec = (unsigned long long*)hbuf;  // alias: rec dead before agg0
    unsigned short* tbuf = (unsigned short*)p; p += (size_t)Npad * 128 * 2;  // bf16 messages
    unsigned short* wbuf = (unsigned short*)p; p += 2 * 16384 * 2;           // Wt0(=Wc0^T), Wt1
    float* bc0 = (float*)p;  p += 128 * 4;
    float* wc2 = (float*)p;  p += 128 * 4;
    float* c2  = (float*)p;  p += 16;
    float* sbuf = (float*)p; p += (size_t)N * 4;
    p = align16(p);
    unsigned* cnt1     = (unsigned*)p; p += (size_t)NC * NB * 4;  // counts -> offsets (in place)
    unsigned* total    = (unsigned*)p; p += (size_t)NB * 4;
    unsigned* padTotal = (unsigned*)p; p += (size_t)NB * 4;
    unsigned* cntg     = (unsigned*)p; p += (size_t)N * 4;
    float* dinv   = (float*)p; p += (size_t)N * 4;
    int* row_ptr  = (int*)p;   p += (size_t)(N + 1) * 4; p = align16(p);
    unsigned* edata = (unsigned*)p;                    // E + 7N + 64 padded records

    dim3 b256(256);
    int nGemm = Npad / 128;                  // 782
    int nPrep = (33025 + 255) / 256;         // 130
    int nScanB = (NB + 255) / 256;           // 4

    // weights prep, then layer-0 GEMM (x @ Wc0 + bc0 -> tbuf)
    prep_kernel<<<nPrep, b256, 0, stream>>>(W1, Wg, b1, W2, bg, b2,
                                            wbuf, wbuf + 16384, wc2, bc0, c2);
    gemm_mfma_kernel<<<nGemm, b256, 0, stream>>>(x, wbuf, bc0, tbuf, N);

    // CSR build (no global atomics)
    bucketCount_kernel<<<NC, b256, 0, stream>>>(col, cnt1, E, NB);
    colScan_kernel<<<nScanB, b256, 0, stream>>>(cnt1, total, NB, NC);
    bucketScatter_kernel<<<NC, b256, 0, stream>>>(row, col, ea, cnt1, total, rec, E, NB);
    nodeCount_kernel<<<NB, b256, 0, stream>>>(rec, total, cntg, dinv, padTotal, N, NB);
    finalize_kernel<<<NB, b256, 0, stream>>>(rec, total, padTotal, cntg, dinv,
                                             row_ptr, edata, N, NB);

    int wave_blocks = (int)(((size_t)N * 64 + 255) / 256);

    // agg0 -> hbuf(fp32); gemm(Wg1) -> tbuf; agg1+project -> sbuf; final scalar gather
    aggregate_kernel<false><<<wave_blocks, b256, 0, stream>>>(
        (const uint2*)tbuf, row_ptr, edata, dinv, bg, nullptr, hbuf, N);
    gemm_mfma_kernel<<<nGemm, b256, 0, stream>>>(hbuf, wbuf + 16384, nullptr, tbuf, N);
    aggregate_kernel<true><<<wave_blocks, b256, 0, stream>>>(
        (const uint2*)tbuf, row_ptr, edata, dinv, bg + 128, wc2, sbuf, N);
    aggFinal_kernel<<<wave_blocks, b256, 0, stream>>>(sbuf, row_ptr, edata, dinv, c2,
                                                      (float*)d_out, N);
}